// Round 1
// baseline (163.946 us; speedup 1.0000x reference)
//
#include <hip/hip_runtime.h>
#include <hip/hip_bf16.h>

// GrantGCN: out = [h, A h] @ W2^T + b2, h = relu([x, A x] @ W1^T + b1)
// A built from edges with numpy semantics:
//   adj[src,dst] = w   (scatter-SET: last edge in order wins per (src,dst))
//   adj[dst,src] += w  (scatter-ADD: all edges accumulate)
// We never materialize A (8192^2 = 256 MB). Instead:
//   A = sum_{winning e} w_e E[src_e,dst_e] + sum_{all e} w_e E[dst_e,src_e]
// "winning" = max edge index among duplicates of (src,dst), resolved via a
// hash table (atomicCAS slot claim + atomicMax on edge id).

#define NN    8192
#define NE    131072
#define XD    32
#define HID   64
#define NC    40
#define TBL   (1u << 19)
#define TMASK (TBL - 1u)
#define EMPTYK 0xFFFFFFFFu

__device__ __forceinline__ unsigned hashk(unsigned k) {
    return (k * 2654435761u) & TMASK;
}

__global__ void hash_insert(const int* __restrict__ src, const int* __restrict__ dst,
                            unsigned* __restrict__ keys, unsigned* __restrict__ vals) {
    int e = blockIdx.x * blockDim.x + threadIdx.x;
    if (e >= NE) return;
    unsigned key = (unsigned)src[e] * (unsigned)NN + (unsigned)dst[e];
    unsigned h = hashk(key);
    while (true) {
        unsigned old = atomicCAS(&keys[h], EMPTYK, key);
        if (old == EMPTYK || old == key) {
            atomicMax(&vals[h], (unsigned)(e + 1));  // e+1 so 0 == "none"
            break;
        }
        h = (h + 1u) & TMASK;
    }
}

__global__ void mark_win(const int* __restrict__ src, const int* __restrict__ dst,
                         const unsigned* __restrict__ keys, const unsigned* __restrict__ vals,
                         unsigned char* __restrict__ flag) {
    int e = blockIdx.x * blockDim.x + threadIdx.x;
    if (e >= NE) return;
    unsigned key = (unsigned)src[e] * (unsigned)NN + (unsigned)dst[e];
    unsigned h = hashk(key);
    while (keys[h] != key) h = (h + 1u) & TMASK;
    flag[e] = (vals[h] == (unsigned)(e + 1)) ? 1u : 0u;
}

// y[NN,F] += A @ x[NN,F], edge-parallel, one thread per (edge, feature).
template <int F>
__global__ void spmm(const int* __restrict__ src, const int* __restrict__ dst,
                     const float* __restrict__ w, const unsigned char* __restrict__ flag,
                     const float* __restrict__ x, float* __restrict__ y) {
    int t = blockIdx.x * blockDim.x + threadIdx.x;
    int e = t / F;
    int f = t % F;
    if (e >= NE) return;
    int s = src[e], d = dst[e];
    float we = w[e];
    // add part: A[dst,src] += w  ->  y[dst] += w * x[src]
    atomicAdd(&y[d * F + f], we * x[s * F + f]);
    // set part (winning edge only): A[src,dst] = w -> y[src] += w * x[dst]
    if (flag[e]) atomicAdd(&y[s * F + f], we * x[d * F + f]);
}

// h[n,c] = relu( sum_j concat(x[n],y1[n])[j] * W1[c,j] + b1[c] ),  c in [0,64)
__global__ void dense1(const float* __restrict__ x, const float* __restrict__ y1,
                       const float* __restrict__ W1, const float* __restrict__ b1,
                       float* __restrict__ h) {
    __shared__ float gc[2 * XD];
    int n = blockIdx.x;
    int t = threadIdx.x;  // 64 threads
    gc[t] = (t < XD) ? x[n * XD + t] : y1[n * XD + (t - XD)];
    __syncthreads();
    float acc = b1[t];
#pragma unroll
    for (int j = 0; j < 2 * XD; ++j) acc += gc[j] * W1[t * (2 * XD) + j];
    h[n * HID + t] = fmaxf(acc, 0.0f);
}

// out[n,c] = sum_j concat(h[n],y2[n])[j] * W2[c,j] + b2[c],  c in [0,40)
__global__ void dense2(const float* __restrict__ h, const float* __restrict__ y2,
                       const float* __restrict__ W2, const float* __restrict__ b2,
                       float* __restrict__ out) {
    __shared__ float gc[2 * HID];
    int n = blockIdx.x;
    int t = threadIdx.x;  // 128 threads
    gc[t] = (t < HID) ? h[n * HID + t] : y2[n * HID + (t - HID)];
    __syncthreads();
    if (t < NC) {
        float acc = b2[t];
#pragma unroll
        for (int j = 0; j < 2 * HID; ++j) acc += gc[j] * W2[t * (2 * HID) + j];
        out[n * NC + t] = acc;
    }
}

extern "C" void kernel_launch(void* const* d_in, const int* in_sizes, int n_in,
                              void* d_out, int out_size, void* d_ws, size_t ws_size,
                              hipStream_t stream) {
    const float* x  = (const float*)d_in[0];
    const int*   ei = (const int*)d_in[1];
    const float* w  = (const float*)d_in[2];
    // d_in[3] is k (always 2 in this problem's setup)
    const float* W1 = (const float*)d_in[4];
    const float* b1 = (const float*)d_in[5];
    const float* W2 = (const float*)d_in[6];
    const float* b2 = (const float*)d_in[7];
    float* out = (float*)d_out;

    char* ws = (char*)d_ws;
    // workspace layout (bytes)
    unsigned*      keys = (unsigned*)(ws + 0);              // 2 MiB
    unsigned*      vals = (unsigned*)(ws + 2097152);        // 2 MiB
    unsigned char* flag = (unsigned char*)(ws + 4194304);   // 128 KiB
    float*         y1   = (float*)(ws + 4325376);           // 1 MiB   (A @ x)
    float*         h    = (float*)(ws + 5373952);           // 2 MiB   (hidden)
    float*         y2   = (float*)(ws + 7471104);           // 2 MiB   (A @ h)
    // total: 9568256 bytes

    const int* src = ei;        // edge_index[0, :]
    const int* dst = ei + NE;   // edge_index[1, :]

    hipMemsetAsync(keys, 0xFF, TBL * sizeof(unsigned), stream);
    hipMemsetAsync(vals, 0x00, TBL * sizeof(unsigned), stream);
    hipMemsetAsync(y1,   0x00, (size_t)NN * XD  * sizeof(float), stream);
    hipMemsetAsync(y2,   0x00, (size_t)NN * HID * sizeof(float), stream);

    hash_insert<<<NE / 256, 256, 0, stream>>>(src, dst, keys, vals);
    mark_win<<<NE / 256, 256, 0, stream>>>(src, dst, keys, vals, flag);

    spmm<XD><<<(NE * XD) / 256, 256, 0, stream>>>(src, dst, w, flag, x, y1);
    dense1<<<NN, HID, 0, stream>>>(x, y1, W1, b1, h);

    spmm<HID><<<(NE * HID) / 256, 256, 0, stream>>>(src, dst, w, flag, h, y2);
    dense2<<<NN, 2 * HID, 0, stream>>>(h, y2, W2, b2, out);
}

// Round 2
// 146.773 us; speedup vs baseline: 1.1170x; 1.1170x over previous
//
#include <hip/hip_runtime.h>
#include <hip/hip_bf16.h>

// GrantGCN: out = [h, A h] @ W2^T + b2, h = relu([x, A x] @ W1^T + b1)
// A built from edges with numpy semantics:
//   adj[src,dst] = w   (scatter-SET: last edge in order wins per (src,dst))
//   adj[dst,src] += w  (scatter-ADD: all edges accumulate)
// Strategy: resolve set-winners via hash table, then build CSR (no dense A),
// then row-gather SpMM fused with the per-node dense layers. No atomics in
// the hot path (round-0 profile: atomic spmm = 114 us, WRITE_SIZE 65 MB from
// cross-XCD atomic coherence traffic).

#define NN    8192
#define NE    131072
#define XD    32
#define HID   64
#define NC    40
#define TBL   (1u << 18)
#define TMASK (TBL - 1u)
#define EMPTYK 0xFFFFFFFFu

__device__ __forceinline__ unsigned hashk(unsigned k) {
    return (k * 2654435761u) & TMASK;
}

__global__ void hash_insert(const int* __restrict__ src, const int* __restrict__ dst,
                            unsigned* __restrict__ keys, unsigned* __restrict__ vals) {
    int e = blockIdx.x * blockDim.x + threadIdx.x;
    if (e >= NE) return;
    unsigned key = (unsigned)src[e] * (unsigned)NN + (unsigned)dst[e];
    unsigned h = hashk(key);
    while (true) {
        unsigned old = atomicCAS(&keys[h], EMPTYK, key);
        if (old == EMPTYK || old == key) {
            atomicMax(&vals[h], (unsigned)(e + 1));  // e+1 so 0 == "none"
            break;
        }
        h = (h + 1u) & TMASK;
    }
}

// flag winners AND count directed degrees in one pass.
// Directed entries: row=dst gets (col=src, w) for EVERY edge (the += part);
// row=src gets (col=dst, w) only for the winning edge (the set part).
__global__ void mark_count(const int* __restrict__ src, const int* __restrict__ dst,
                           const unsigned* __restrict__ keys, const unsigned* __restrict__ vals,
                           unsigned char* __restrict__ flag, unsigned* __restrict__ deg) {
    int e = blockIdx.x * blockDim.x + threadIdx.x;
    if (e >= NE) return;
    int s = src[e], d = dst[e];
    unsigned key = (unsigned)s * (unsigned)NN + (unsigned)d;
    unsigned h = hashk(key);
    while (keys[h] != key) h = (h + 1u) & TMASK;
    bool win = (vals[h] == (unsigned)(e + 1));
    flag[e] = win ? 1u : 0u;
    atomicAdd(&deg[d], 1u);
    if (win) atomicAdd(&deg[s], 1u);
}

// exclusive prefix sum over 8192 degrees; single block of 1024 x 8 elems.
__global__ __launch_bounds__(1024) void scan_deg(const unsigned* __restrict__ deg,
                                                 unsigned* __restrict__ row_start,
                                                 unsigned* __restrict__ cur) {
    __shared__ unsigned sums[1024];
    int t = threadIdx.x;
    unsigned local[8];
    unsigned s = 0;
#pragma unroll
    for (int i = 0; i < 8; ++i) { local[i] = deg[t * 8 + i]; s += local[i]; }
    sums[t] = s;
    __syncthreads();
    for (int off = 1; off < 1024; off <<= 1) {
        unsigned v = 0;
        if (t >= off) v = sums[t - off];
        __syncthreads();
        if (t >= off) sums[t] += v;
        __syncthreads();
    }
    unsigned base = (t > 0) ? sums[t - 1] : 0u;
#pragma unroll
    for (int i = 0; i < 8; ++i) {
        row_start[t * 8 + i] = base;
        cur[t * 8 + i] = base;
        base += local[i];
    }
    if (t == 1023) row_start[NN] = base;
}

__global__ void scatter(const int* __restrict__ src, const int* __restrict__ dst,
                        const float* __restrict__ w, const unsigned char* __restrict__ flag,
                        unsigned* __restrict__ cur, int* __restrict__ col,
                        float* __restrict__ val) {
    int e = blockIdx.x * blockDim.x + threadIdx.x;
    if (e >= NE) return;
    int s = src[e], d = dst[e];
    float we = w[e];
    unsigned p = atomicAdd(&cur[d], 1u);
    col[p] = s; val[p] = we;
    if (flag[e]) {
        unsigned q = atomicAdd(&cur[s], 1u);
        col[q] = d; val[q] = we;
    }
}

// fusedA: per 32-lane group, gather y1[n,:] = (A x)[n,:], stage concat(x_n,y1_n)
// in LDS, then dense1 + relu -> h.  Block = 256 threads = 8 nodes.
__global__ __launch_bounds__(256) void fusedA(const unsigned* __restrict__ row_start,
                                              const int* __restrict__ col,
                                              const float* __restrict__ val,
                                              const float* __restrict__ x,
                                              const float* __restrict__ W1,
                                              const float* __restrict__ b1,
                                              float* __restrict__ h) {
    __shared__ float gc[8][2 * XD];
    int t = threadIdx.x;
    int g = t >> 5;      // node sub-group 0..7
    int f = t & 31;      // feature
    int n = blockIdx.x * 8 + g;
    unsigned b = row_start[n], e = row_start[n + 1];
    float acc = 0.f;
    unsigned i = b;
    for (; i + 2 <= e; i += 2) {
        int c0 = col[i], c1 = col[i + 1];
        float v0 = val[i], v1 = val[i + 1];
        acc += v0 * x[c0 * XD + f] + v1 * x[c1 * XD + f];
    }
    if (i < e) acc += val[i] * x[col[i] * XD + f];
    gc[g][f] = x[n * XD + f];
    gc[g][XD + f] = acc;
    __syncthreads();
    // 512 outputs: 8 nodes x 64 hidden; 2 per thread
#pragma unroll
    for (int o = 0; o < 2; ++o) {
        int idx = o * 256 + t;
        int gg = idx >> 6;
        int c = idx & 63;
        const float* wr = &W1[c * (2 * XD)];
        float a = b1[c];
#pragma unroll
        for (int j = 0; j < 2 * XD; ++j) a += gc[gg][j] * wr[j];
        h[(blockIdx.x * 8 + gg) * HID + c] = fmaxf(a, 0.f);
    }
}

// fusedB: per 64-lane group, gather y2[n,:] = (A h)[n,:], stage concat(h_n,y2_n)
// in LDS, then dense2 -> out.  Block = 256 threads = 4 nodes.
__global__ __launch_bounds__(256) void fusedB(const unsigned* __restrict__ row_start,
                                              const int* __restrict__ col,
                                              const float* __restrict__ val,
                                              const float* __restrict__ h,
                                              const float* __restrict__ W2,
                                              const float* __restrict__ b2,
                                              float* __restrict__ out) {
    __shared__ float gc[4][2 * HID];
    int t = threadIdx.x;
    int g = t >> 6;      // node sub-group 0..3
    int f = t & 63;      // feature
    int n = blockIdx.x * 4 + g;
    unsigned b = row_start[n], e = row_start[n + 1];
    float acc = 0.f;
    unsigned i = b;
    for (; i + 2 <= e; i += 2) {
        int c0 = col[i], c1 = col[i + 1];
        float v0 = val[i], v1 = val[i + 1];
        acc += v0 * h[c0 * HID + f] + v1 * h[c1 * HID + f];
    }
    if (i < e) acc += val[i] * h[col[i] * HID + f];
    gc[g][f] = h[n * HID + f];
    gc[g][HID + f] = acc;
    __syncthreads();
    // 160 outputs: 4 nodes x 40 classes
    if (t < 4 * NC) {
        int gg = t / NC;
        int c = t - gg * NC;
        const float* wr = &W2[c * (2 * HID)];
        float a = b2[c];
#pragma unroll
        for (int j = 0; j < 2 * HID; ++j) a += gc[gg][j] * wr[j];
        out[(blockIdx.x * 4 + gg) * NC + c] = a;
    }
}

extern "C" void kernel_launch(void* const* d_in, const int* in_sizes, int n_in,
                              void* d_out, int out_size, void* d_ws, size_t ws_size,
                              hipStream_t stream) {
    const float* x  = (const float*)d_in[0];
    const int*   ei = (const int*)d_in[1];
    const float* w  = (const float*)d_in[2];
    // d_in[3] is k (always 2)
    const float* W1 = (const float*)d_in[4];
    const float* b1 = (const float*)d_in[5];
    const float* W2 = (const float*)d_in[6];
    const float* b2 = (const float*)d_in[7];
    float* out = (float*)d_out;

    char* ws = (char*)d_ws;
    // layout (bytes); keys/vals are dead after mark_count, col/val alias them.
    unsigned*      keys      = (unsigned*)(ws + 0);                 // 1 MiB
    unsigned*      vals      = (unsigned*)(ws + (1 << 20));         // 1 MiB
    int*           col       = (int*)(ws + 0);                      // 1 MiB (alias keys)
    float*         val       = (float*)(ws + (1 << 20));            // 1 MiB (alias vals)
    unsigned*      deg       = (unsigned*)(ws + (2 << 20));         // 32 KiB
    unsigned char* flag      = (unsigned char*)(ws + (2 << 20) + (32 << 10));   // 128 KiB
    unsigned*      row_start = (unsigned*)(ws + (2 << 20) + (160 << 10));       // 36 KiB
    unsigned*      cur       = (unsigned*)(ws + (2 << 20) + (196 << 10));       // 32 KiB
    float*         h         = (float*)(ws + (2 << 20) + (228 << 10));          // 2 MiB
    // total ~4.4 MiB

    const int* src = ei;        // edge_index[0, :]
    const int* dst = ei + NE;   // edge_index[1, :]

    hipMemsetAsync(keys, 0xFF, 1 << 20, stream);
    hipMemsetAsync(vals, 0x00, (1 << 20) + (NN * 4), stream);  // vals + deg (contiguous)

    hash_insert<<<NE / 256, 256, 0, stream>>>(src, dst, keys, vals);
    mark_count<<<NE / 256, 256, 0, stream>>>(src, dst, keys, vals, flag, deg);
    scan_deg<<<1, 1024, 0, stream>>>(deg, row_start, cur);
    scatter<<<NE / 256, 256, 0, stream>>>(src, dst, w, flag, cur, col, val);

    fusedA<<<NN / 8, 256, 0, stream>>>(row_start, col, val, x, W1, b1, h);
    fusedB<<<NN / 4, 256, 0, stream>>>(row_start, col, val, h, W2, b2, out);
}

// Round 3
// 125.654 us; speedup vs baseline: 1.3047x; 1.1681x over previous
//
#include <hip/hip_runtime.h>
#include <hip/hip_bf16.h>

// GrantGCN: out = [h, A h] @ W2^T + b2, h = relu([x, A x] @ W1^T + b1)
// A built from edges with numpy semantics:
//   adj[src,dst] = w   (scatter-SET: last edge in order wins per (src,dst))
//   adj[dst,src] += w  (scatter-ADD: all edges accumulate)
// CSR built per call (hash resolves set-winners), then wave-per-node gather
// SpMM fused with the dense layers. Round-2 profile: gather was latency-bound
// (VALUBusy 7%, HBM 2%), so gather is float4-per-lane with 8 edges in flight
// per wave + shfl_xor reduction.

#define NN    8192
#define NE    131072
#define XD    32
#define HID   64
#define NC    40
#define TBL   (1u << 18)
#define TMASK (TBL - 1u)
#define EMPTYK 0xFFFFFFFFu

__device__ __forceinline__ unsigned hashk(unsigned k) {
    return (k * 2654435761u) & TMASK;
}

__global__ void hash_insert(const int* __restrict__ src, const int* __restrict__ dst,
                            unsigned* __restrict__ keys, unsigned* __restrict__ vals) {
    int e = blockIdx.x * blockDim.x + threadIdx.x;
    if (e >= NE) return;
    unsigned key = (unsigned)src[e] * (unsigned)NN + (unsigned)dst[e];
    unsigned h = hashk(key);
    while (true) {
        unsigned old = atomicCAS(&keys[h], EMPTYK, key);
        if (old == EMPTYK || old == key) {
            atomicMax(&vals[h], (unsigned)(e + 1));  // e+1 so 0 == "none"
            break;
        }
        h = (h + 1u) & TMASK;
    }
}

// flag winners AND count directed degrees in one pass.
__global__ void mark_count(const int* __restrict__ src, const int* __restrict__ dst,
                           const unsigned* __restrict__ keys, const unsigned* __restrict__ vals,
                           unsigned char* __restrict__ flag, unsigned* __restrict__ deg) {
    int e = blockIdx.x * blockDim.x + threadIdx.x;
    if (e >= NE) return;
    int s = src[e], d = dst[e];
    unsigned key = (unsigned)s * (unsigned)NN + (unsigned)d;
    unsigned h = hashk(key);
    while (keys[h] != key) h = (h + 1u) & TMASK;
    bool win = (vals[h] == (unsigned)(e + 1));
    flag[e] = win ? 1u : 0u;
    atomicAdd(&deg[d], 1u);
    if (win) atomicAdd(&deg[s], 1u);
}

// exclusive prefix sum over 8192 degrees; single block of 1024 x 8 elems.
__global__ __launch_bounds__(1024) void scan_deg(const unsigned* __restrict__ deg,
                                                 unsigned* __restrict__ row_start,
                                                 unsigned* __restrict__ cur) {
    __shared__ unsigned sums[1024];
    int t = threadIdx.x;
    unsigned local[8];
    unsigned s = 0;
#pragma unroll
    for (int i = 0; i < 8; ++i) { local[i] = deg[t * 8 + i]; s += local[i]; }
    sums[t] = s;
    __syncthreads();
    for (int off = 1; off < 1024; off <<= 1) {
        unsigned v = 0;
        if (t >= off) v = sums[t - off];
        __syncthreads();
        if (t >= off) sums[t] += v;
        __syncthreads();
    }
    unsigned base = (t > 0) ? sums[t - 1] : 0u;
#pragma unroll
    for (int i = 0; i < 8; ++i) {
        row_start[t * 8 + i] = base;
        cur[t * 8 + i] = base;
        base += local[i];
    }
    if (t == 1023) row_start[NN] = base;
}

__global__ void scatter(const int* __restrict__ src, const int* __restrict__ dst,
                        const float* __restrict__ w, const unsigned char* __restrict__ flag,
                        unsigned* __restrict__ cur, int* __restrict__ col,
                        float* __restrict__ val) {
    int e = blockIdx.x * blockDim.x + threadIdx.x;
    if (e >= NE) return;
    int s = src[e], d = dst[e];
    float we = w[e];
    unsigned p = atomicAdd(&cur[d], 1u);
    col[p] = s; val[p] = we;
    if (flag[e]) {
        unsigned q = atomicAdd(&cur[s], 1u);
        col[q] = d; val[q] = we;
    }
}

// fusedA: one 64-lane wave per node. Lane = (edge-slot eq 0..7, feature-quad
// fq 0..7). Gather y1 = (A x)[n] as float4 per lane, xor-reduce over edge
// slots, stage concat(x_n, y1_n) in LDS, dense1+relu -> h (lane = hidden unit).
__global__ __launch_bounds__(256) void fusedA(const unsigned* __restrict__ row_start,
                                              const int* __restrict__ col,
                                              const float* __restrict__ val,
                                              const float* __restrict__ x,
                                              const float* __restrict__ W1,
                                              const float* __restrict__ b1,
                                              float* __restrict__ h) {
    __shared__ float4 gc[4][16];   // per node: quads 0..7 = x row, 8..15 = y1 row
    int t = threadIdx.x;
    int g = t >> 6;                // wave = node sub-group 0..3
    int l = t & 63;
    int n = blockIdx.x * 4 + g;
    int eq = l >> 3;               // edge slot
    int fq = l & 7;                // feature quad
    const float4* x4 = (const float4*)x;
    unsigned b = row_start[n], e = row_start[n + 1];
    float4 acc = make_float4(0.f, 0.f, 0.f, 0.f);
    for (unsigned i = b + eq; i < e; i += 8) {
        int c = col[i];
        float v = val[i];
        float4 xv = x4[c * 8 + fq];
        acc.x += v * xv.x; acc.y += v * xv.y; acc.z += v * xv.z; acc.w += v * xv.w;
    }
#pragma unroll
    for (int m = 8; m < 64; m <<= 1) {
        acc.x += __shfl_xor(acc.x, m);
        acc.y += __shfl_xor(acc.y, m);
        acc.z += __shfl_xor(acc.z, m);
        acc.w += __shfl_xor(acc.w, m);
    }
    if (l < 8) {
        gc[g][l] = x4[n * 8 + l];
        gc[g][8 + l] = acc;        // lane l holds the sum for fq == l
    }
    __syncthreads();
    // dense1: lane l = hidden unit l of node n
    const float4* w4 = (const float4*)&W1[l * (2 * XD)];
    float a = b1[l];
#pragma unroll
    for (int j = 0; j < 16; ++j) {
        float4 gv = gc[g][j];
        float4 wv = w4[j];
        a += gv.x * wv.x + gv.y * wv.y + gv.z * wv.z + gv.w * wv.w;
    }
    h[n * HID + l] = fmaxf(a, 0.f);
}

// fusedB: one 64-lane wave per node. Lane = (edge-slot eq 0..3, quad fq 0..15).
__global__ __launch_bounds__(256) void fusedB(const unsigned* __restrict__ row_start,
                                              const int* __restrict__ col,
                                              const float* __restrict__ val,
                                              const float* __restrict__ h,
                                              const float* __restrict__ W2,
                                              const float* __restrict__ b2,
                                              float* __restrict__ out) {
    __shared__ float4 gc[4][32];   // per node: quads 0..15 = h row, 16..31 = y2 row
    int t = threadIdx.x;
    int g = t >> 6;
    int l = t & 63;
    int n = blockIdx.x * 4 + g;
    int eq = l >> 4;               // edge slot 0..3
    int fq = l & 15;               // feature quad 0..15
    const float4* h4 = (const float4*)h;
    unsigned b = row_start[n], e = row_start[n + 1];
    float4 acc = make_float4(0.f, 0.f, 0.f, 0.f);
    for (unsigned i = b + eq; i < e; i += 4) {
        int c = col[i];
        float v = val[i];
        float4 hv = h4[c * 16 + fq];
        acc.x += v * hv.x; acc.y += v * hv.y; acc.z += v * hv.z; acc.w += v * hv.w;
    }
#pragma unroll
    for (int m = 16; m < 64; m <<= 1) {
        acc.x += __shfl_xor(acc.x, m);
        acc.y += __shfl_xor(acc.y, m);
        acc.z += __shfl_xor(acc.z, m);
        acc.w += __shfl_xor(acc.w, m);
    }
    if (l < 16) {
        gc[g][l] = h4[n * 16 + l];
        gc[g][16 + l] = acc;       // lane l holds the sum for fq == l
    }
    __syncthreads();
    if (l < NC) {
        const float4* w4 = (const float4*)&W2[l * (2 * HID)];
        float a = b2[l];
#pragma unroll
        for (int j = 0; j < 32; ++j) {
            float4 gv = gc[g][j];
            float4 wv = w4[j];
            a += gv.x * wv.x + gv.y * wv.y + gv.z * wv.z + gv.w * wv.w;
        }
        out[n * NC + l] = a;
    }
}

extern "C" void kernel_launch(void* const* d_in, const int* in_sizes, int n_in,
                              void* d_out, int out_size, void* d_ws, size_t ws_size,
                              hipStream_t stream) {
    const float* x  = (const float*)d_in[0];
    const int*   ei = (const int*)d_in[1];
    const float* w  = (const float*)d_in[2];
    // d_in[3] is k (always 2)
    const float* W1 = (const float*)d_in[4];
    const float* b1 = (const float*)d_in[5];
    const float* W2 = (const float*)d_in[6];
    const float* b2 = (const float*)d_in[7];
    float* out = (float*)d_out;

    char* ws = (char*)d_ws;
    // layout (bytes); keys/vals are dead after mark_count, col/val alias them.
    unsigned*      keys      = (unsigned*)(ws + 0);                 // 1 MiB
    unsigned*      vals      = (unsigned*)(ws + (1 << 20));         // 1 MiB
    int*           col       = (int*)(ws + 0);                      // 1 MiB (alias keys)
    float*         val       = (float*)(ws + (1 << 20));            // 1 MiB (alias vals)
    unsigned*      deg       = (unsigned*)(ws + (2 << 20));         // 32 KiB
    unsigned char* flag      = (unsigned char*)(ws + (2 << 20) + (32 << 10));   // 128 KiB
    unsigned*      row_start = (unsigned*)(ws + (2 << 20) + (160 << 10));       // 36 KiB
    unsigned*      cur       = (unsigned*)(ws + (2 << 20) + (196 << 10));       // 32 KiB
    float*         h         = (float*)(ws + (2 << 20) + (228 << 10));          // 2 MiB
    // total ~4.4 MiB

    const int* src = ei;        // edge_index[0, :]
    const int* dst = ei + NE;   // edge_index[1, :]

    hipMemsetAsync(keys, 0xFF, 1 << 20, stream);
    hipMemsetAsync(vals, 0x00, (1 << 20) + (NN * 4), stream);  // vals + deg (contiguous)

    hash_insert<<<NE / 256, 256, 0, stream>>>(src, dst, keys, vals);
    mark_count<<<NE / 256, 256, 0, stream>>>(src, dst, keys, vals, flag, deg);
    scan_deg<<<1, 1024, 0, stream>>>(deg, row_start, cur);
    scatter<<<NE / 256, 256, 0, stream>>>(src, dst, w, flag, cur, col, val);

    fusedA<<<NN / 4, 256, 0, stream>>>(row_start, col, val, x, W1, b1, h);
    fusedB<<<NN / 4, 256, 0, stream>>>(row_start, col, val, h, W2, b2, out);
}

// Round 4
// 123.554 us; speedup vs baseline: 1.3269x; 1.0170x over previous
//
#include <hip/hip_runtime.h>
#include <hip/hip_bf16.h>

// GrantGCN: out = [h, A h] @ W2^T + b2, h = relu([x, A x] @ W1^T + b1)
// A built from edges with numpy semantics:
//   adj[src,dst] = w   (scatter-SET: last edge in order wins per (src,dst))
//   adj[dst,src] += w  (scatter-ADD: all edges accumulate)
// CSR built per call (hash resolves set-winners), then wave-per-node gather
// SpMM fused with the dense layers.
// Round-3 profile: hipMemsetAsync's fillBufferAligned was 2x41us (tiny-grid,
// latency-bound) -> replaced with one custom uint4 init kernel.

#define NN    8192
#define NE    131072
#define XD    32
#define HID   64
#define NC    40
#define TBL   (1u << 18)
#define TMASK (TBL - 1u)
#define EMPTYK 0xFFFFFFFFu

__device__ __forceinline__ unsigned hashk(unsigned k) {
    return (k * 2654435761u) & TMASK;
}

// keys <- 0xFF (TBL dwords), vals+deg <- 0 (TBL+NN dwords, contiguous)
#define K4  (TBL / 4)          // 65536 uint4
#define VD4 ((TBL + NN) / 4)   // 67584 uint4
__global__ void init_tables(uint4* __restrict__ keys, uint4* __restrict__ valsdeg) {
    int t = blockIdx.x * blockDim.x + threadIdx.x;
    if (t < K4)  keys[t]    = make_uint4(~0u, ~0u, ~0u, ~0u);
    if (t < VD4) valsdeg[t] = make_uint4(0u, 0u, 0u, 0u);
}

__global__ void hash_insert(const int* __restrict__ src, const int* __restrict__ dst,
                            unsigned* __restrict__ keys, unsigned* __restrict__ vals) {
    int e = blockIdx.x * blockDim.x + threadIdx.x;
    if (e >= NE) return;
    unsigned key = (unsigned)src[e] * (unsigned)NN + (unsigned)dst[e];
    unsigned h = hashk(key);
    while (true) {
        unsigned old = atomicCAS(&keys[h], EMPTYK, key);
        if (old == EMPTYK || old == key) {
            atomicMax(&vals[h], (unsigned)(e + 1));  // e+1 so 0 == "none"
            break;
        }
        h = (h + 1u) & TMASK;
    }
}

// flag winners AND count directed degrees in one pass.
__global__ void mark_count(const int* __restrict__ src, const int* __restrict__ dst,
                           const unsigned* __restrict__ keys, const unsigned* __restrict__ vals,
                           unsigned char* __restrict__ flag, unsigned* __restrict__ deg) {
    int e = blockIdx.x * blockDim.x + threadIdx.x;
    if (e >= NE) return;
    int s = src[e], d = dst[e];
    unsigned key = (unsigned)s * (unsigned)NN + (unsigned)d;
    unsigned h = hashk(key);
    while (keys[h] != key) h = (h + 1u) & TMASK;
    bool win = (vals[h] == (unsigned)(e + 1));
    flag[e] = win ? 1u : 0u;
    atomicAdd(&deg[d], 1u);
    if (win) atomicAdd(&deg[s], 1u);
}

// exclusive prefix sum over 8192 degrees; single block of 1024 x 8 elems.
__global__ __launch_bounds__(1024) void scan_deg(const unsigned* __restrict__ deg,
                                                 unsigned* __restrict__ row_start,
                                                 unsigned* __restrict__ cur) {
    __shared__ unsigned sums[1024];
    int t = threadIdx.x;
    unsigned local[8];
    unsigned s = 0;
#pragma unroll
    for (int i = 0; i < 8; ++i) { local[i] = deg[t * 8 + i]; s += local[i]; }
    sums[t] = s;
    __syncthreads();
    for (int off = 1; off < 1024; off <<= 1) {
        unsigned v = 0;
        if (t >= off) v = sums[t - off];
        __syncthreads();
        if (t >= off) sums[t] += v;
        __syncthreads();
    }
    unsigned base = (t > 0) ? sums[t - 1] : 0u;
#pragma unroll
    for (int i = 0; i < 8; ++i) {
        row_start[t * 8 + i] = base;
        cur[t * 8 + i] = base;
        base += local[i];
    }
    if (t == 1023) row_start[NN] = base;
}

__global__ void scatter(const int* __restrict__ src, const int* __restrict__ dst,
                        const float* __restrict__ w, const unsigned char* __restrict__ flag,
                        unsigned* __restrict__ cur, int* __restrict__ col,
                        float* __restrict__ val) {
    int e = blockIdx.x * blockDim.x + threadIdx.x;
    if (e >= NE) return;
    int s = src[e], d = dst[e];
    float we = w[e];
    unsigned p = atomicAdd(&cur[d], 1u);
    col[p] = s; val[p] = we;
    if (flag[e]) {
        unsigned q = atomicAdd(&cur[s], 1u);
        col[q] = d; val[q] = we;
    }
}

// fusedA: one 64-lane wave per node. Lane = (edge-slot eq 0..7, feature-quad
// fq 0..7). Gather y1 = (A x)[n] as float4 per lane, xor-reduce over edge
// slots, stage concat(x_n, y1_n) in LDS, dense1+relu -> h (lane = hidden unit).
__global__ __launch_bounds__(256) void fusedA(const unsigned* __restrict__ row_start,
                                              const int* __restrict__ col,
                                              const float* __restrict__ val,
                                              const float* __restrict__ x,
                                              const float* __restrict__ W1,
                                              const float* __restrict__ b1,
                                              float* __restrict__ h) {
    __shared__ float4 gc[4][16];   // per node: quads 0..7 = x row, 8..15 = y1 row
    int t = threadIdx.x;
    int g = t >> 6;                // wave = node sub-group 0..3
    int l = t & 63;
    int n = blockIdx.x * 4 + g;
    int eq = l >> 3;               // edge slot
    int fq = l & 7;                // feature quad
    const float4* x4 = (const float4*)x;
    unsigned b = row_start[n], e = row_start[n + 1];
    float4 acc = make_float4(0.f, 0.f, 0.f, 0.f);
    for (unsigned i = b + eq; i < e; i += 8) {
        int c = col[i];
        float v = val[i];
        float4 xv = x4[c * 8 + fq];
        acc.x += v * xv.x; acc.y += v * xv.y; acc.z += v * xv.z; acc.w += v * xv.w;
    }
#pragma unroll
    for (int m = 8; m < 64; m <<= 1) {
        acc.x += __shfl_xor(acc.x, m);
        acc.y += __shfl_xor(acc.y, m);
        acc.z += __shfl_xor(acc.z, m);
        acc.w += __shfl_xor(acc.w, m);
    }
    if (l < 8) {
        gc[g][l] = x4[n * 8 + l];
        gc[g][8 + l] = acc;        // lane l holds the sum for fq == l
    }
    __syncthreads();
    // dense1: lane l = hidden unit l of node n
    const float4* w4 = (const float4*)&W1[l * (2 * XD)];
    float a = b1[l];
#pragma unroll
    for (int j = 0; j < 16; ++j) {
        float4 gv = gc[g][j];
        float4 wv = w4[j];
        a += gv.x * wv.x + gv.y * wv.y + gv.z * wv.z + gv.w * wv.w;
    }
    h[n * HID + l] = fmaxf(a, 0.f);
}

// fusedB: one 64-lane wave per node. Lane = (edge-slot eq 0..3, quad fq 0..15).
__global__ __launch_bounds__(256) void fusedB(const unsigned* __restrict__ row_start,
                                              const int* __restrict__ col,
                                              const float* __restrict__ val,
                                              const float* __restrict__ h,
                                              const float* __restrict__ W2,
                                              const float* __restrict__ b2,
                                              float* __restrict__ out) {
    __shared__ float4 gc[4][32];   // per node: quads 0..15 = h row, 16..31 = y2 row
    int t = threadIdx.x;
    int g = t >> 6;
    int l = t & 63;
    int n = blockIdx.x * 4 + g;
    int eq = l >> 4;               // edge slot 0..3
    int fq = l & 15;               // feature quad 0..15
    const float4* h4 = (const float4*)h;
    unsigned b = row_start[n], e = row_start[n + 1];
    float4 acc = make_float4(0.f, 0.f, 0.f, 0.f);
    for (unsigned i = b + eq; i < e; i += 4) {
        int c = col[i];
        float v = val[i];
        float4 hv = h4[c * 16 + fq];
        acc.x += v * hv.x; acc.y += v * hv.y; acc.z += v * hv.z; acc.w += v * hv.w;
    }
#pragma unroll
    for (int m = 16; m < 64; m <<= 1) {
        acc.x += __shfl_xor(acc.x, m);
        acc.y += __shfl_xor(acc.y, m);
        acc.z += __shfl_xor(acc.z, m);
        acc.w += __shfl_xor(acc.w, m);
    }
    if (l < 16) {
        gc[g][l] = h4[n * 16 + l];
        gc[g][16 + l] = acc;       // lane l holds the sum for fq == l
    }
    __syncthreads();
    if (l < NC) {
        const float4* w4 = (const float4*)&W2[l * (2 * HID)];
        float a = b2[l];
#pragma unroll
        for (int j = 0; j < 32; ++j) {
            float4 gv = gc[g][j];
            float4 wv = w4[j];
            a += gv.x * wv.x + gv.y * wv.y + gv.z * wv.z + gv.w * wv.w;
        }
        out[n * NC + l] = a;
    }
}

extern "C" void kernel_launch(void* const* d_in, const int* in_sizes, int n_in,
                              void* d_out, int out_size, void* d_ws, size_t ws_size,
                              hipStream_t stream) {
    const float* x  = (const float*)d_in[0];
    const int*   ei = (const int*)d_in[1];
    const float* w  = (const float*)d_in[2];
    // d_in[3] is k (always 2)
    const float* W1 = (const float*)d_in[4];
    const float* b1 = (const float*)d_in[5];
    const float* W2 = (const float*)d_in[6];
    const float* b2 = (const float*)d_in[7];
    float* out = (float*)d_out;

    char* ws = (char*)d_ws;
    // layout (bytes); keys/vals are dead after mark_count, col/val alias them.
    unsigned*      keys      = (unsigned*)(ws + 0);                 // 1 MiB
    unsigned*      vals      = (unsigned*)(ws + (1 << 20));         // 1 MiB
    int*           col       = (int*)(ws + 0);                      // 1 MiB (alias keys)
    float*         val       = (float*)(ws + (1 << 20));            // 1 MiB (alias vals)
    unsigned*      deg       = (unsigned*)(ws + (2 << 20));         // 32 KiB (contiguous after vals!)
    unsigned char* flag      = (unsigned char*)(ws + (2 << 20) + (32 << 10));   // 128 KiB
    unsigned*      row_start = (unsigned*)(ws + (2 << 20) + (160 << 10));       // 36 KiB
    unsigned*      cur       = (unsigned*)(ws + (2 << 20) + (196 << 10));       // 32 KiB
    float*         h         = (float*)(ws + (2 << 20) + (228 << 10));          // 2 MiB
    // total ~4.4 MiB

    const int* src = ei;        // edge_index[0, :]
    const int* dst = ei + NE;   // edge_index[1, :]

    init_tables<<<(VD4 + 255) / 256, 256, 0, stream>>>((uint4*)keys, (uint4*)vals);

    hash_insert<<<NE / 256, 256, 0, stream>>>(src, dst, keys, vals);
    mark_count<<<NE / 256, 256, 0, stream>>>(src, dst, keys, vals, flag, deg);
    scan_deg<<<1, 1024, 0, stream>>>(deg, row_start, cur);
    scatter<<<NE / 256, 256, 0, stream>>>(src, dst, w, flag, cur, col, val);

    fusedA<<<NN / 4, 256, 0, stream>>>(row_start, col, val, x, W1, b1, h);
    fusedB<<<NN / 4, 256, 0, stream>>>(row_start, col, val, h, W2, b2, out);
}